// Round 1
// baseline (213.094 us; speedup 1.0000x reference)
//
#include <hip/hip_runtime.h>
#include <hip/hip_bf16.h>
#include <math.h>

#define B_ 8
#define T_ 2048
#define C_ 1024
#define H_ 64
#define M_ (B_*T_)      // 16384
#define BM 64
#define BKP 72          // padded LDS row stride (elements): 144B = multiple of 16B

typedef __attribute__((ext_vector_type(8))) short short8;
typedef __attribute__((ext_vector_type(4))) short short4v;
typedef __attribute__((ext_vector_type(4))) float f32x4;

__device__ __forceinline__ unsigned short f2bf(float f) {
    unsigned int u = __builtin_bit_cast(unsigned int, f);
    u += 0x7FFFu + ((u >> 16) & 1u);      // RNE
    return (unsigned short)(u >> 16);
}

// ---------------- Kernel 1: fused QKV projection ----------------
// C[m][n] = X[m][k] * W[k][n], n in [0,192): [Wk | Wq(*1/32) | Wv]
__global__ __launch_bounds__(256) void qkv_proj(
    const float* __restrict__ x,
    const float* __restrict__ Wk,
    const float* __restrict__ Wq,
    const float* __restrict__ Wv,
    unsigned short* __restrict__ kb,
    unsigned short* __restrict__ qb,
    unsigned short* __restrict__ vb)
{
    __shared__ __align__(16) unsigned short Xs[BM][BKP];    // [row][k]
    __shared__ __align__(16) unsigned short Ws[192][BKP];   // transposed: [n][k]

    const int tid  = threadIdx.x;
    const int wid  = tid >> 6;
    const int lane = tid & 63;
    const int lr   = lane & 15;
    const int lg   = lane >> 4;
    const int m0   = blockIdx.x * BM;

    const float* Wsrc[3] = {Wk, Wq, Wv};

    f32x4 acc[4][3];
    for (int r = 0; r < 4; ++r)
        for (int c = 0; c < 3; ++c)
            acc[r][c] = (f32x4){0.f, 0.f, 0.f, 0.f};

    for (int k0 = 0; k0 < C_; k0 += 64) {
        __syncthreads();
        // stage X tile: 64 rows x 64 k, fp32 -> bf16
        for (int p = 0; p < 4; ++p) {
            int a = (p * 256 + tid) * 4;         // 0..4095
            int r = a >> 6, c = a & 63;
            float4 v = *reinterpret_cast<const float4*>(x + (size_t)(m0 + r) * C_ + k0 + c);
            short4v pk;
            pk.x = (short)f2bf(v.x); pk.y = (short)f2bf(v.y);
            pk.z = (short)f2bf(v.z); pk.w = (short)f2bf(v.w);
            *reinterpret_cast<short4v*>(&Xs[r][c]) = pk;
        }
        // stage W transposed: Ws[n][k], 192 x 64
        for (int p = 0; p < 12; ++p) {
            int a   = p * 256 + tid;             // 0..3071
            int n   = a % 192;
            int kr0 = (a / 192) * 4;
            const float* s = Wsrc[n >> 6] + (size_t)(k0 + kr0) * H_ + (n & 63);
            float sc = (n >= 64 && n < 128) ? 0.03125f : 1.0f;  // fold C^-0.5 into q
            short4v pk;
            pk.x = (short)f2bf(s[0]   * sc);
            pk.y = (short)f2bf(s[64]  * sc);
            pk.z = (short)f2bf(s[128] * sc);
            pk.w = (short)f2bf(s[192] * sc);
            *reinterpret_cast<short4v*>(&Ws[n][kr0]) = pk;
        }
        __syncthreads();

        for (int kc = 0; kc < 2; ++kc) {
            short8 af[4], bfr[3];
            for (int rt = 0; rt < 4; ++rt)
                af[rt] = *reinterpret_cast<const short8*>(&Xs[rt * 16 + lr][kc * 32 + lg * 8]);
            for (int ct = 0; ct < 3; ++ct)
                bfr[ct] = *reinterpret_cast<const short8*>(&Ws[(wid * 3 + ct) * 16 + lr][kc * 32 + lg * 8]);
            for (int rt = 0; rt < 4; ++rt)
                for (int ct = 0; ct < 3; ++ct)
                    acc[rt][ct] = __builtin_amdgcn_mfma_f32_16x16x32_bf16(
                        af[rt], bfr[ct], acc[rt][ct], 0, 0, 0);
        }
    }

    // epilogue: D layout col=lane&15, row=(lane>>4)*4+reg
    for (int rt = 0; rt < 4; ++rt) {
        for (int ct = 0; ct < 3; ++ct) {
            int n = (wid * 3 + ct) * 16 + lr;
            unsigned short* dst = (n < 64) ? kb : (n < 128 ? qb : vb);
            int col = n & 63;
            for (int i = 0; i < 4; ++i) {
                int row = m0 + rt * 16 + lg * 4 + i;
                dst[(size_t)row * H_ + col] = f2bf(acc[rt][ct][i]);
            }
        }
    }
}

// ---------------- Kernel 2: causal flash attention ----------------
__global__ __launch_bounds__(256) void attn(
    const unsigned short* __restrict__ kb,
    const unsigned short* __restrict__ qb,
    const unsigned short* __restrict__ vb,
    float* __restrict__ out)
{
    __shared__ __align__(16) unsigned short Ks[64][BKP];       // [key][d]
    __shared__ __align__(16) unsigned short Vt[64][BKP];       // [d][key]
    __shared__ __align__(16) unsigned short Ps[4][16][BKP];    // per-wave P tile [qrow][key]

    const int tid  = threadIdx.x;
    const int wid  = tid >> 6;
    const int lane = tid & 63;
    const int lr   = lane & 15;
    const int lg   = lane >> 4;
    const int b    = blockIdx.y;
    const int q0   = blockIdx.x * 64;
    const int wq0  = q0 + wid * 16;

    const size_t base = (size_t)b * T_ * H_;

    // Q fragments held in registers (A operand: row = lane&15, k = (lane>>4)*8+j)
    short8 qf[2];
    for (int kc = 0; kc < 2; ++kc)
        qf[kc] = *reinterpret_cast<const short8*>(
            qb + base + (size_t)(wq0 + lr) * H_ + kc * 32 + lg * 8);

    f32x4 o[4];
    float mrun[4], lrun[4];
    for (int dt = 0; dt < 4; ++dt) o[dt] = (f32x4){0.f, 0.f, 0.f, 0.f};
    for (int i = 0; i < 4; ++i) { mrun[i] = -INFINITY; lrun[i] = 0.f; }

    for (int kv0 = 0; kv0 <= q0; kv0 += 64) {
        __syncthreads();
        // stage K tile and transposed V tile
        for (int p = 0; p < 2; ++p) {
            int a = (p * 256 + tid) * 8;     // 0..4095
            int r = a >> 6, c = a & 63;      // r = key, c = d0
            short8 kv = *reinterpret_cast<const short8*>(kb + base + (size_t)(kv0 + r) * H_ + c);
            *reinterpret_cast<short8*>(&Ks[r][c]) = kv;
            short8 vv = *reinterpret_cast<const short8*>(vb + base + (size_t)(kv0 + r) * H_ + c);
            for (int j = 0; j < 8; ++j)
                Vt[c + j][r] = (unsigned short)vv[j];
        }
        __syncthreads();

        // S = Q * K^T   (16 q-rows x 64 keys per wave)
        f32x4 s[4];
        for (int kt = 0; kt < 4; ++kt) s[kt] = (f32x4){0.f, 0.f, 0.f, 0.f};
        for (int kc = 0; kc < 2; ++kc) {
            for (int kt = 0; kt < 4; ++kt) {
                short8 kf = *reinterpret_cast<const short8*>(&Ks[kt * 16 + lr][kc * 32 + lg * 8]);
                s[kt] = __builtin_amdgcn_mfma_f32_16x16x32_bf16(qf[kc], kf, s[kt], 0, 0, 0);
            }
        }

        // causal mask + online softmax (lane holds rows lg*4+i, key col = lr per tile)
        for (int i = 0; i < 4; ++i) {
            int row = wq0 + lg * 4 + i;
            float sv[4];
            float mx = -INFINITY;
            for (int kt = 0; kt < 4; ++kt) {
                int key = kv0 + kt * 16 + lr;
                float v = (key <= row) ? s[kt][i] : -INFINITY;
                sv[kt] = v;
                mx = fmaxf(mx, v);
            }
            for (int d = 8; d; d >>= 1) mx = fmaxf(mx, __shfl_xor(mx, d));
            float mn  = fmaxf(mrun[i], mx);
            float fac = __expf(mrun[i] - mn);
            float rs  = 0.f;
            for (int kt = 0; kt < 4; ++kt) {
                float p = __expf(sv[kt] - mn);
                rs += p;
                Ps[wid][lg * 4 + i][kt * 16 + lr] = f2bf(p);
            }
            for (int d = 8; d; d >>= 1) rs += __shfl_xor(rs, d);
            lrun[i] = lrun[i] * fac + rs;
            mrun[i] = mn;
            for (int dt = 0; dt < 4; ++dt)
                o[dt][i] *= fac;
        }

        // O += P * V   (P via wave-private LDS re-layout; V from transposed tile)
        for (int kc = 0; kc < 2; ++kc) {
            short8 pf = *reinterpret_cast<const short8*>(&Ps[wid][lr][kc * 32 + lg * 8]);
            for (int dt = 0; dt < 4; ++dt) {
                short8 vf = *reinterpret_cast<const short8*>(&Vt[dt * 16 + lr][kc * 32 + lg * 8]);
                o[dt] = __builtin_amdgcn_mfma_f32_16x16x32_bf16(pf, vf, o[dt], 0, 0, 0);
            }
        }
    }

    // epilogue: normalize and store fp32
    for (int i = 0; i < 4; ++i) {
        float inv = 1.0f / lrun[i];
        int row = wq0 + lg * 4 + i;
        for (int dt = 0; dt < 4; ++dt)
            out[base + (size_t)row * H_ + dt * 16 + lr] = o[dt][i] * inv;
    }
}

extern "C" void kernel_launch(void* const* d_in, const int* in_sizes, int n_in,
                              void* d_out, int out_size, void* d_ws, size_t ws_size,
                              hipStream_t stream) {
    const float* x  = (const float*)d_in[0];
    const float* Wk = (const float*)d_in[1];
    const float* Wq = (const float*)d_in[2];
    const float* Wv = (const float*)d_in[3];
    float* out = (float*)d_out;

    unsigned short* kb = (unsigned short*)d_ws;
    unsigned short* qb = kb + (size_t)M_ * H_;
    unsigned short* vb = qb + (size_t)M_ * H_;

    qkv_proj<<<dim3(M_ / BM), 256, 0, stream>>>(x, Wk, Wq, Wv, kb, qb, vb);
    attn<<<dim3(T_ / 64, B_), 256, 0, stream>>>(kb, qb, vb, out);
}

// Round 2
// 187.520 us; speedup vs baseline: 1.1364x; 1.1364x over previous
//
#include <hip/hip_runtime.h>
#include <hip/hip_bf16.h>
#include <math.h>

#define B_ 8
#define T_ 2048
#define C_ 1024
#define H_ 64
#define M_ (B_*T_)      // 16384
#define BMQ 32

typedef __attribute__((ext_vector_type(8))) short short8;
typedef __attribute__((ext_vector_type(4))) float f32x4;
typedef unsigned int u32;

__device__ __forceinline__ unsigned short f2bf(float f) {
    u32 u = __builtin_bit_cast(u32, f);
    u += 0x7FFFu + ((u >> 16) & 1u);      // RNE
    return (unsigned short)(u >> 16);
}

__device__ __forceinline__ void gl2lds16(const void* g, void* l) {
    __builtin_amdgcn_global_load_lds(
        (const __attribute__((address_space(1))) u32*)g,
        (__attribute__((address_space(3))) u32*)l, 16, 0, 0);
}

// ---------------- Kernel 0: W -> bf16, transposed [n][k], q-scaled, XOR-swizzled ----------------
// wb row n (2048 B): byte col for element k is (k2 & ~127) | ((k2 & 127) ^ ((n&7)<<4))
__global__ __launch_bounds__(256) void wconv(
    const float* __restrict__ Wk, const float* __restrict__ Wq,
    const float* __restrict__ Wv, unsigned short* __restrict__ wb)
{
    int idx = blockIdx.x * 256 + threadIdx.x;     // 0..196607
    int n = idx % 192, k = idx / 192;
    const float* src = (n < 64) ? Wk : (n < 128 ? Wq : Wv);
    float sc = (n >= 64 && n < 128) ? 0.03125f : 1.0f;
    float v = src[(size_t)k * H_ + (n & 63)] * sc;
    int k2 = k * 2;
    int dst = (k2 & ~127) | ((k2 & 127) ^ ((n & 7) << 4));
    *(unsigned short*)((char*)wb + (size_t)n * 2048 + dst) = f2bf(v);
}

// ---------------- Kernel 1: QKV GEMM ----------------
// C[m][n] = X[m][k] * W^T[n][k],  n in [0,192): [k | q(*1/32) | v]
__global__ __launch_bounds__(256) void qkv_mm(
    const float* __restrict__ x, const unsigned short* __restrict__ wb,
    unsigned short* __restrict__ kb, unsigned short* __restrict__ qb,
    unsigned short* __restrict__ vT)
{
    __shared__ __align__(16) unsigned short Xs[32][72];          // padded bf16
    __shared__ __align__(16) unsigned short Ws[2][192 * 64];     // linear, swizzled content

    const int tid = threadIdx.x;
    const int wid = tid >> 6;
    const int lane = tid & 63;
    const int lr = lane & 15;
    const int lg = lane >> 4;
    const int m0 = blockIdx.x * BMQ;

    const int xrow = tid >> 3;
    const int xcol = (tid & 7) * 8;
    const float* xbase = x + (size_t)(m0 + xrow) * C_ + xcol;

    f32x4 acc[2][3];
    for (int r = 0; r < 2; ++r)
        for (int c = 0; c < 3; ++c)
            acc[r][c] = (f32x4){0.f, 0.f, 0.f, 0.f};

    // prologue: issue W tile 0 + prefetch X tile 0 into regs
    float4 xr0 = *reinterpret_cast<const float4*>(xbase);
    float4 xr1 = *reinterpret_cast<const float4*>(xbase + 4);
    {
        for (int p = 0; p < 6; ++p) {
            int c = p * 256 + tid;
            int n = c >> 3, c16 = c & 7;
            gl2lds16((const char*)wb + (size_t)n * 2048 + c16 * 16,
                     (char*)&Ws[0][0] + c * 16);
        }
    }

    for (int t = 0; t < 16; ++t) {
        __syncthreads();   // (a) drains xr/W-tile-t loads; all waves done reading prev LDS
        // write X tile t (bf16) into padded LDS
        short8 xw;
        xw[0] = (short)f2bf(xr0.x); xw[1] = (short)f2bf(xr0.y);
        xw[2] = (short)f2bf(xr0.z); xw[3] = (short)f2bf(xr0.w);
        xw[4] = (short)f2bf(xr1.x); xw[5] = (short)f2bf(xr1.y);
        xw[6] = (short)f2bf(xr1.z); xw[7] = (short)f2bf(xr1.w);
        *reinterpret_cast<short8*>(&Xs[xrow][xcol]) = xw;
        __syncthreads();   // (b) X visible

        // issue next tile's loads; they stay in flight under the MFMA phase
        if (t < 15) {
            xr0 = *reinterpret_cast<const float4*>(xbase + (t + 1) * 64);
            xr1 = *reinterpret_cast<const float4*>(xbase + (t + 1) * 64 + 4);
            int buf = (t + 1) & 1;
            for (int p = 0; p < 6; ++p) {
                int c = p * 256 + tid;
                int n = c >> 3, c16 = c & 7;
                gl2lds16((const char*)wb + (size_t)n * 2048 + (t + 1) * 128 + c16 * 16,
                         (char*)&Ws[buf][0] + c * 16);
            }
        }

        const char* wbuf = (const char*)&Ws[t & 1][0];
        for (int kc = 0; kc < 2; ++kc) {
            short8 af[2], bfr[3];
            for (int rt = 0; rt < 2; ++rt)
                af[rt] = *reinterpret_cast<const short8*>(&Xs[rt * 16 + lr][kc * 32 + lg * 8]);
            for (int ct = 0; ct < 3; ++ct) {
                int n = (wid * 3 + ct) * 16 + lr;
                int cb = (kc * 64 + lg * 16) ^ ((n & 7) << 4);
                bfr[ct] = *reinterpret_cast<const short8*>(wbuf + n * 128 + cb);
            }
            for (int rt = 0; rt < 2; ++rt)
                for (int ct = 0; ct < 3; ++ct)
                    acc[rt][ct] = __builtin_amdgcn_mfma_f32_16x16x32_bf16(
                        af[rt], bfr[ct], acc[rt][ct], 0, 0, 0);
        }
    }

    // epilogue: D layout col=lane&15, row=(lane>>4)*4+reg
    for (int rt = 0; rt < 2; ++rt) {
        for (int ct = 0; ct < 3; ++ct) {
            int n = (wid * 3 + ct) * 16 + lr;
            int col = n & 63;
            for (int i = 0; i < 4; ++i) {
                int m = m0 + rt * 16 + lg * 4 + i;
                unsigned short val = f2bf(acc[rt][ct][i]);
                if (n < 64)       kb[(size_t)m * H_ + col] = val;
                else if (n < 128) qb[(size_t)m * H_ + col] = val;
                else              vT[(size_t)(m >> 11) * (64 * T_) + (size_t)col * T_ + (m & (T_ - 1))] = val;
            }
        }
    }
}

// ---------------- Kernel 2: causal flash attention, global-direct, balanced ----------------
// One wave per block; wave handles q-tile pair (bx, 127-bx): constant ~33 kv-steps.
__global__ __launch_bounds__(64) void attn2(
    const unsigned short* __restrict__ kb,
    const unsigned short* __restrict__ qb,
    const unsigned short* __restrict__ vT,
    float* __restrict__ out)
{
    __shared__ __align__(16) unsigned short Ps[16][72];

    const int lane = threadIdx.x;
    const int lr = lane & 15;
    const int lg = lane >> 4;
    const int b = blockIdx.y;
    const int bx = blockIdx.x;
    const size_t base = (size_t)b * T_ * H_;
    const unsigned short* vTb = vT + (size_t)b * 64 * T_;

    for (int ph = 0; ph < 2; ++ph) {
        const int tile = ph ? (127 - bx) : bx;
        const int q0w = tile * 16;

        short8 qf[2];
        for (int kc = 0; kc < 2; ++kc)
            qf[kc] = *reinterpret_cast<const short8*>(
                qb + base + (size_t)(q0w + lr) * H_ + kc * 32 + lg * 8);

        f32x4 o[4];
        float mrun[4], lrun[4];
        for (int dt = 0; dt < 4; ++dt) o[dt] = (f32x4){0.f, 0.f, 0.f, 0.f};
        for (int i = 0; i < 4; ++i) { mrun[i] = -INFINITY; lrun[i] = 0.f; }

        for (int kv0 = 0; kv0 <= q0w; kv0 += 64) {
            // S = Q K^T  (16 q-rows x 64 keys), K frags direct from L2
            f32x4 s[4];
            for (int kt = 0; kt < 4; ++kt) s[kt] = (f32x4){0.f, 0.f, 0.f, 0.f};
            for (int kc = 0; kc < 2; ++kc) {
                for (int kt = 0; kt < 4; ++kt) {
                    short8 kf = *reinterpret_cast<const short8*>(
                        kb + base + (size_t)(kv0 + kt * 16 + lr) * H_ + kc * 32 + lg * 8);
                    s[kt] = __builtin_amdgcn_mfma_f32_16x16x32_bf16(qf[kc], kf, s[kt], 0, 0, 0);
                }
            }

            // causal mask + online softmax
            for (int i = 0; i < 4; ++i) {
                int row = q0w + lg * 4 + i;
                float sv[4];
                float mx = -INFINITY;
                for (int kt = 0; kt < 4; ++kt) {
                    int key = kv0 + kt * 16 + lr;
                    float v = (key <= row) ? s[kt][i] : -INFINITY;
                    sv[kt] = v;
                    mx = fmaxf(mx, v);
                }
                for (int d = 8; d; d >>= 1) mx = fmaxf(mx, __shfl_xor(mx, d));
                float mn  = fmaxf(mrun[i], mx);
                float fac = __expf(mrun[i] - mn);
                float rs  = 0.f;
                for (int kt = 0; kt < 4; ++kt) {
                    float p = __expf(sv[kt] - mn);
                    rs += p;
                    Ps[lg * 4 + i][kt * 16 + lr] = f2bf(p);
                }
                for (int d = 8; d; d >>= 1) rs += __shfl_xor(rs, d);
                lrun[i] = lrun[i] * fac + rs;
                mrun[i] = mn;
                for (int dt = 0; dt < 4; ++dt)
                    o[dt][i] *= fac;
            }

            // O += P * V, V^T frags direct (contiguous 16 B)
            for (int kc = 0; kc < 2; ++kc) {
                short8 pf = *reinterpret_cast<const short8*>(&Ps[lr][kc * 32 + lg * 8]);
                for (int dt = 0; dt < 4; ++dt) {
                    short8 vf = *reinterpret_cast<const short8*>(
                        vTb + (size_t)(dt * 16 + lr) * T_ + kv0 + kc * 32 + lg * 8);
                    o[dt] = __builtin_amdgcn_mfma_f32_16x16x32_bf16(pf, vf, o[dt], 0, 0, 0);
                }
            }
        }

        for (int i = 0; i < 4; ++i) {
            float inv = 1.0f / lrun[i];
            int row = q0w + lg * 4 + i;
            for (int dt = 0; dt < 4; ++dt)
                out[base + (size_t)row * H_ + dt * 16 + lr] = o[dt][i] * inv;
        }
    }
}

extern "C" void kernel_launch(void* const* d_in, const int* in_sizes, int n_in,
                              void* d_out, int out_size, void* d_ws, size_t ws_size,
                              hipStream_t stream) {
    const float* x  = (const float*)d_in[0];
    const float* Wk = (const float*)d_in[1];
    const float* Wq = (const float*)d_in[2];
    const float* Wv = (const float*)d_in[3];
    float* out = (float*)d_out;

    unsigned short* kb = (unsigned short*)d_ws;              // 1 M elems
    unsigned short* qb = kb + (size_t)M_ * H_;               // 1 M elems
    unsigned short* vT = qb + (size_t)M_ * H_;               // 1 M elems ([b][d][t])
    unsigned short* wb = vT + (size_t)M_ * H_;               // 192*1024 elems

    wconv<<<768, 256, 0, stream>>>(Wk, Wq, Wv, wb);
    qkv_mm<<<M_ / BMQ, 256, 0, stream>>>(x, wb, kb, qb, vT);
    attn2<<<dim3(64, B_), 64, 0, stream>>>(kb, qb, vT, out);
}